// Round 5
// baseline (161.977 us; speedup 1.0000x reference)
//
#include <hip/hip_runtime.h>

typedef unsigned short u16;
typedef unsigned int   u32;
typedef unsigned long long u64;

typedef __attribute__((ext_vector_type(8))) short bf16x8;
typedef __attribute__((ext_vector_type(4))) float f32x4;
typedef __attribute__((ext_vector_type(2))) float f32x2;

#define BB 4
#define MM 2048
#define NN 16384
#define DD 64

__device__ __forceinline__ u16 f2bf(float f) {
    union { float f; u32 u; } v; v.f = f;
    u32 r = v.u + 0x7fffu + ((v.u >> 16) & 1u);   // RNE
    return (u16)(r >> 16);
}

// pack two floats to bf16 pair by truncation: lo16=trunc(lo), hi16=trunc(hi)
__device__ __forceinline__ u32 pack_trunc(float hi, float lo) {
    union { float f; u32 u; } a, b; a.f = hi; b.f = lo;
    return __builtin_amdgcn_perm(a.u, b.u, 0x07060302);
}

// RNE pack of two floats into a bf16 pair
__device__ __forceinline__ u32 pack_rne(float hi, float lo) {
    return (u32)f2bf(lo) | ((u32)f2bf(hi) << 16);
}

__device__ __forceinline__ bf16x8 pack8(float4 p, float4 q) {
    bf16x8 v;
    v[0] = (short)f2bf(p.x); v[1] = (short)f2bf(p.y);
    v[2] = (short)f2bf(p.z); v[3] = (short)f2bf(p.w);
    v[4] = (short)f2bf(q.x); v[5] = (short)f2bf(q.y);
    v[6] = (short)f2bf(q.z); v[7] = (short)f2bf(q.w);
    return v;
}

// ===========================================================================
// ws layout:
//   [0, 1M)      fdT  bf16 [b][d][m]        (feat_down transposed)
//   [1M, +128K)  xyzP pair-SoA: per pair {-2x0,-2x1,-2y0,-2y1}{-2z0,-2z1,w0,w1}
//   [.., +32K)   w1s  bf16 frag-major [kg*8+ot][lane][8]
//   [.., +16K)   w2s  bf16 frag-major [kg*4+ot][lane][8]
//   [.., +1.5K)  bn consts float[384] = A1[128] Bc1[128] A2[64] Bc2[64]
// ===========================================================================
#define OFF_FDT   0ull
#define OFF_XYZP  1048576ull
#define OFF_W1S   1179648ull
#define OFF_W2S   1212416ull
#define OFF_BN    1228800ull
#define WS_NEED   1230336ull

// ---------------------------------------------------------------------------
// prep6: 285 blocks x 256. (unchanged)
// ---------------------------------------------------------------------------
__global__ __launch_bounds__(256)
void prep6_kernel(const float* __restrict__ xyz_down,
                  const float* __restrict__ feat_down,
                  const float* __restrict__ W1, const float* __restrict__ b1,
                  const float* __restrict__ g1, const float* __restrict__ be1,
                  const float* __restrict__ m1, const float* __restrict__ v1,
                  const float* __restrict__ W2, const float* __restrict__ b2,
                  const float* __restrict__ g2, const float* __restrict__ be2,
                  const float* __restrict__ m2, const float* __restrict__ v2,
                  u16* __restrict__ fdT, float4* __restrict__ xyzP,
                  u16* __restrict__ w1s, u16* __restrict__ w2s,
                  float* __restrict__ bnbuf)
{
    const int blk = blockIdx.x, t = threadIdx.x;
    if (blk < 256) {
        __shared__ u16 T[32 * 72];
        const int b = blk >> 6, m0 = (blk & 63) * 32;
        {
            const int row = t >> 3, seg = (t & 7) * 8;
            const float4* src = (const float4*)(feat_down + ((size_t)(b * MM + m0 + row)) * 64 + seg);
            float4 v0 = src[0], v1 = src[1];
            bf16x8 pk = pack8(v0, v1);
            *(bf16x8*)&T[row * 72 + seg] = pk;
        }
        __syncthreads();
        {
            const int d = t & 63, w = t >> 6;
            union { u16 h[8]; uint4 q; } o;
#pragma unroll
            for (int j = 0; j < 8; j++) o.h[j] = T[(w * 8 + j) * 72 + d];
            *(uint4*)&fdT[((size_t)(b * 64 + d)) * MM + m0 + w * 8] = o.q;
        }
    } else if (blk < 272) {
        int g = (blk - 256) * 256 + t;
        int b = g >> 10, p = g & 1023;
        const float* s = xyz_down + ((size_t)b * MM + 2 * p) * 3;
        float x0 = s[0], y0 = s[1], z0 = s[2];
        float x1 = s[3], y1 = s[4], z1 = s[5];
        float w0 = x0 * x0 + y0 * y0 + z0 * z0 + 1e-8f;
        float w1v = x1 * x1 + y1 * y1 + z1 * z1 + 1e-8f;
        xyzP[(size_t)g * 2 + 0] = make_float4(-2.f * x0, -2.f * x1, -2.f * y0, -2.f * y1);
        xyzP[(size_t)g * 2 + 1] = make_float4(-2.f * z0, -2.f * z1, w0, w1v);
    } else if (blk < 280) {
        int slot = (blk - 272) * 256 + t;
        int f = slot >> 6, l = slot & 63;
        int kg = f >> 3, ot = f & 7;
        int o = ot * 16 + (l & 15), c = kg * 32 + (l >> 4) * 8;
        const float4* src = (const float4*)(W1 + (size_t)o * 128 + c);
        bf16x8 v = pack8(src[0], src[1]);
        *(bf16x8*)&w1s[(size_t)slot * 8] = v;
    } else if (blk < 284) {
        int slot = (blk - 280) * 256 + t;
        int f = slot >> 6, l = slot & 63;
        int kg = f >> 2, ot = f & 3;
        int o = ot * 16 + (l & 15), c = kg * 32 + (l >> 4) * 8;
        const float4* src = (const float4*)(W2 + (size_t)o * 128 + c);
        bf16x8 v = pack8(src[0], src[1]);
        *(bf16x8*)&w2s[(size_t)slot * 8] = v;
    } else {
        if (t < 128) {
            float a = g1[t] * rsqrtf(v1[t] + 1e-5f);
            bnbuf[t] = a;
            bnbuf[128 + t] = (b1[t] - m1[t]) * a + be1[t];
        } else if (t < 192) {
            int o = t - 128;
            float a = g2[o] * rsqrtf(v2[o] + 1e-5f);
            bnbuf[256 + o] = a;
            bnbuf[320 + o] = (b2[o] - m2[o]) * a + be2[o];
        }
    }
}

// ---------------------------------------------------------------------------
// fused11: fat-wave variant. Rounds 2-4 proved the loop is neither occupancy-
// nor fence-bound: all pipes <45% busy with 16 phase-locked waves/CU convoying
// on LDS then VALU each chunk. Invert the decomposition: 256-row blocks,
// 4 waves x 64 rows (rt=4), grid=256 (1 block/CU).
//  - bb frags shared across 4 row-tiles -> per-CU LDS read traffic HALVES
//    (32KB vs 64KB per chunk); staging writes + fdT L2 reads halve too.
//  - 16 independent dist chains per wave per kk -> single-wave ILP keeps the
//    VALU pipe busy without TLP (which rounds 2-4 proved useless here).
//  - no h-split -> cross-half reduction deleted.
//  - keeps fused10's no-vmem-drain loop skeleton (reg prefetch c+2,
//    ds_write c+1, lgkmcnt-only + raw s_barrier).
// LDS: xh[256][136] (69.6KB) aliases interp bufs (21.5KB). 1 block/CU.
// ---------------------------------------------------------------------------
__global__ __launch_bounds__(256, 1)
void fused11_kernel(const float* __restrict__ xyz_up,
                    const u16* __restrict__ fdT,
                    const float4* __restrict__ xyzP,
                    const float* __restrict__ feat_up,
                    const u16* __restrict__ w1s,
                    const u16* __restrict__ w2s,
                    const float* __restrict__ bnbuf,
                    float* __restrict__ out)
{
    // aliased LDS: interp {ftbuf[2][64*72] u16 (18432B) | xyzb[2][384] f32
    // (3072B)} overlays MLP {xh[256][136] u16 == of[256][68] f32 (69632B)}
    __shared__ __align__(16) char smem[69632];
    __shared__ float bnl[384];
    u16*   const ftbuf = (u16*)smem;               // [2][64*72]
    float* const xyzb  = (float*)(smem + 18432);   // [2][384]
    u16*   const xh    = (u16*)smem;               // [256][136]
    float* const of    = (float*)smem;             // [256][68]

    const int tid  = threadIdx.x;
    const int b    = blockIdx.x >> 6;
    const int n0   = (blockIdx.x & 63) * 256;
    const int w    = tid >> 6;
    const int lane = tid & 63;
    const int q    = lane >> 4;
    const int nl   = lane & 15;
    const int wb   = w * 64;       // wave's row base (64 rows per wave)

    bnl[tid] = bnbuf[tid];
    if (tid < 128) bnl[256 + tid] = bnbuf[256 + tid];

    // per-row xyz_up (4 row-tiles of 16 per wave)
    float ax[4], ay[4], az[4];
    f32x2 a22[4];
#pragma unroll
    for (int rt = 0; rt < 4; rt++) {
        const int row = n0 + wb + rt * 16 + nl;
        const float* xu = xyz_up + ((size_t)(b * NN + row)) * 3;
        ax[rt] = xu[0]; ay[rt] = xu[1]; az[rt] = xu[2];
        float a2 = ax[rt] * ax[rt] + ay[rt] * ay[rt] + az[rt] * az[rt];
        a22[rt] = (f32x2){a2, a2};
    }
    const f32x2 eps2 = (f32x2){1e-8f, 1e-8f};

    f32x4 acc[4][4];
#pragma unroll
    for (int rt = 0; rt < 4; rt++)
#pragma unroll
        for (int i = 0; i < 4; i++) acc[rt][i] = (f32x4){0.f, 0.f, 0.f, 0.f};
    f32x4 accd[4];
#pragma unroll
    for (int rt = 0; rt < 4; rt++) accd[rt] = (f32x4){0.f, 0.f, 0.f, 0.f};

    bf16x8 ones;
#pragma unroll
    for (int i = 0; i < 8; i++) ones[i] = (short)0x3F80;   // bf16 1.0

    // staging identities (256 threads): ftbuf 64d x 64m, 16 u16 per thread
    const int sd = tid >> 2, sms = (tid & 3) * 16;
    const u16* fsrc = fdT + ((size_t)(b * 64 + sd)) * MM + sms;
    const float4* xsrc = xyzP + ((size_t)b * 1024 + (tid >> 1)) * 2 + (tid & 1);
    const int xoff = (tid >> 1) * 12 + (tid & 1) * 4;

    uint4  rf0, rf1;   // staged feat regs for chunk c+1
    float4 rx;         // staged xyz regs (tid<64 only)

    {   // prologue: chunk 0 -> LDS, chunk 1 -> regs
        uint4 a0 = *(const uint4*)(fsrc);
        uint4 a1 = *(const uint4*)(fsrc + 8);
        *(uint4*)&ftbuf[sd * 72 + sms]     = a0;
        *(uint4*)&ftbuf[sd * 72 + sms + 8] = a1;
        if (tid < 64) {
            float4 x0 = xsrc[0];
            *(float4*)&xyzb[xoff] = x0;
        }
        rf0 = *(const uint4*)(fsrc + 64);
        rf1 = *(const uint4*)(fsrc + 72);
        if (tid < 64) rx = xsrc[64];
        __builtin_amdgcn_sched_barrier(0);
        asm volatile("s_waitcnt lgkmcnt(0)" ::: "memory");
        __builtin_amdgcn_s_barrier();
        __builtin_amdgcn_sched_barrier(0);
    }

    int cur = 0;
    for (int c = 0; c < 32; ++c) {
        const int nxt = cur ^ 1;

        // 1. write chunk c+1 (regs, loaded a full body ago) into LDS[nxt]
        if (c + 1 < 32) {
            *(uint4*)&ftbuf[nxt * 4608 + sd * 72 + sms]     = rf0;
            *(uint4*)&ftbuf[nxt * 4608 + sd * 72 + sms + 8] = rf1;
            if (tid < 64) *(float4*)&xyzb[nxt * 384 + xoff] = rx;
        }
        // 2. issue loads for chunk c+2; in flight across the raw barrier
        if (c + 2 < 32) {
            rf0 = *(const uint4*)(fsrc + (size_t)(c + 2) * 64);
            rf1 = *(const uint4*)(fsrc + (size_t)(c + 2) * 64 + 8);
            if (tid < 64) rx = xsrc[(size_t)(c + 2) * 64];
        }

        // 3. compute chunk c from LDS[cur]: 2 kk-halves x 4 row-tiles
#pragma unroll
        for (int kk = 0; kk < 2; kk++) {
            bf16x8 bb[4];
#pragma unroll
            for (int dt = 0; dt < 4; dt++)
                bb[dt] = *(bf16x8*)&ftbuf[cur * 4608 + (dt * 16 + nl) * 72 + kk * 32 + q * 8];
#pragma unroll
            for (int rt = 0; rt < 4; rt++) {
                u32 fr[4];
#pragma unroll
                for (int jp = 0; jp < 4; jp++) {
                    const int pi = kk * 16 + q * 4 + jp;
                    const float* base = &xyzb[cur * 384 + pi * 12];
                    float4 ld0 = *(const float4*)(base);       // {-2x0,-2x1,-2y0,-2y1}
                    float4 ld1 = *(const float4*)(base + 4);   // {-2z0,-2z1, w0, w1}
                    f32x2 px = (f32x2){ld0.x, ld0.y};
                    f32x2 py = (f32x2){ld0.z, ld0.w};
                    f32x2 pz = (f32x2){ld1.x, ld1.y};
                    f32x2 pw = (f32x2){ld1.z, ld1.w};
                    f32x2 d = __builtin_elementwise_fma(px, (f32x2){ax[rt], ax[rt]},
                              __builtin_elementwise_fma(py, (f32x2){ay[rt], ay[rt]},
                              __builtin_elementwise_fma(pz, (f32x2){az[rt], az[rt]},
                                                        pw + a22[rt])));
                    d = __builtin_elementwise_max(d, eps2);
                    float r0 = __builtin_amdgcn_rcpf(d.x);
                    float r1 = __builtin_amdgcn_rcpf(d.y);
                    fr[jp] = pack_trunc(r1, r0);
                }
                union { u32 u[4]; bf16x8 v; } af;
                af.u[0] = fr[0]; af.u[1] = fr[1];
                af.u[2] = fr[2]; af.u[3] = fr[3];
#pragma unroll
                for (int dt = 0; dt < 4; dt++)
                    acc[rt][dt] = __builtin_amdgcn_mfma_f32_16x16x32_bf16(af.v, bb[dt], acc[rt][dt], 0, 0, 0);
                accd[rt] = __builtin_amdgcn_mfma_f32_16x16x32_bf16(af.v, ones, accd[rt], 0, 0, 0);
            }
        }

        // 4. LDS-visibility wait + RAW barrier (global loads stay in flight)
        __builtin_amdgcn_sched_barrier(0);
        asm volatile("s_waitcnt lgkmcnt(0)" ::: "memory");
        __builtin_amdgcn_s_barrier();
        __builtin_amdgcn_sched_barrier(0);
        cur = nxt;
    }

    __syncthreads();   // protect smem alias: all interp LDS reads done

    // normalize, write interp bf16 into xh cols 64..127 (wave-private rows)
#pragma unroll
    for (int rt = 0; rt < 4; rt++)
#pragma unroll
    for (int reg = 0; reg < 4; reg++) {
        float inv = 1.0f / accd[rt][reg];
        int row = wb + rt * 16 + q * 4 + reg;
#pragma unroll
        for (int dt = 0; dt < 4; dt++)
            xh[row * 136 + 64 + dt * 16 + nl] = f2bf(acc[rt][dt][reg] * inv);
    }

    // feat_up bf16 into xh cols 0..63: 4 passes x 64 rows (cross-wave rows)
    {
        const int fr_ = tid >> 2, fsg = (tid & 3) * 16;
#pragma unroll
        for (int p = 0; p < 4; p++) {
            const int r = p * 64 + fr_;
            const float4* fup = (const float4*)(feat_up + ((size_t)(b * NN + n0 + r)) * 64 + fsg);
            float4 f0 = fup[0], f1 = fup[1], f2 = fup[2], f3 = fup[3];
            uint4 o0, o1;
            o0.x = pack_rne(f0.y, f0.x); o0.y = pack_rne(f0.w, f0.z);
            o0.z = pack_rne(f1.y, f1.x); o0.w = pack_rne(f1.w, f1.z);
            o1.x = pack_rne(f2.y, f2.x); o1.y = pack_rne(f2.w, f2.z);
            o1.z = pack_rne(f3.y, f3.x); o1.w = pack_rne(f3.w, f3.z);
            uint4* xd = (uint4*)&xh[r * 136 + fsg];
            xd[0] = o0; xd[1] = o1;
        }
    }
    __syncthreads();

    // ---------------- MLP: per wave, 4 sub-tiles of 16 rows ----------------
#pragma unroll
    for (int st = 0; st < 4; st++) {
        const int rowA = wb + st * 16;

        // GEMM1: x(16x128) @ W1^T -> h
        f32x4 acc1[8];
#pragma unroll
        for (int i = 0; i < 8; i++) acc1[i] = (f32x4){0.f, 0.f, 0.f, 0.f};
#pragma unroll
        for (int kg = 0; kg < 4; kg++) {
            bf16x8 afr = *(bf16x8*)&xh[(rowA + nl) * 136 + kg * 32 + q * 8];
#pragma unroll
            for (int ot = 0; ot < 8; ot++) {
                bf16x8 bf = *(const bf16x8*)(w1s + ((size_t)(kg * 8 + ot) * 64 + lane) * 8);
                acc1[ot] = __builtin_amdgcn_mfma_f32_16x16x32_bf16(afr, bf, acc1[ot], 0, 0, 0);
            }
        }
        // BN1 + ReLU -> bf16 h back into xh (wave-private rows -> no barrier)
#pragma unroll
        for (int ot = 0; ot < 8; ot++) {
            int o = ot * 16 + nl;
            float aa = bnl[o], bc = bnl[128 + o];
#pragma unroll
            for (int reg = 0; reg < 4; reg++) {
                float v = fmaxf(fmaf(acc1[ot][reg], aa, bc), 0.f);
                xh[(rowA + q * 4 + reg) * 136 + o] = f2bf(v);
            }
        }

        // GEMM2: h(16x128) @ W2^T -> out
        f32x4 acc2[4];
#pragma unroll
        for (int i = 0; i < 4; i++) acc2[i] = (f32x4){0.f, 0.f, 0.f, 0.f};
#pragma unroll
        for (int kg = 0; kg < 4; kg++) {
            bf16x8 afr = *(bf16x8*)&xh[(rowA + nl) * 136 + kg * 32 + q * 8];
#pragma unroll
            for (int ot = 0; ot < 4; ot++) {
                bf16x8 bf = *(const bf16x8*)(w2s + ((size_t)(kg * 4 + ot) * 64 + lane) * 8);
                acc2[ot] = __builtin_amdgcn_mfma_f32_16x16x32_bf16(afr, bf, acc2[ot], 0, 0, 0);
            }
        }
        // BN2 -> f32 tile (of view; same rows, read-before-write in program order)
#pragma unroll
        for (int ot = 0; ot < 4; ot++) {
            int o = ot * 16 + nl;
            float aa = bnl[256 + o], bc = bnl[320 + o];
#pragma unroll
            for (int reg = 0; reg < 4; reg++)
                of[(rowA + q * 4 + reg) * 68 + o] = fmaf(acc2[ot][reg], aa, bc);
        }
    }

    // out store: wave-private rows, 4 passes of 16 rows
    {
        const int rr = lane >> 2, sg = (lane & 3) * 16;
#pragma unroll
        for (int p = 0; p < 4; p++) {
            const int r = wb + p * 16 + rr;
            const float4* sf = (const float4*)&of[r * 68 + sg];
            float4* dst = (float4*)(out + ((size_t)(b * NN + n0 + r)) * 64 + sg);
#pragma unroll
            for (int i = 0; i < 4; i++) dst[i] = sf[i];
        }
    }
}

// ===========================================================================
// Fallback (round-1 kernels, proven): used when ws_size < WS_NEED.
// ===========================================================================
#define TN 128
#define BM 64
#define RS 72
#define FS 72

__global__ __launch_bounds__(256, 3)
void interp_kernel(const float* __restrict__ xyz_down,
                   const float* __restrict__ xyz_up,
                   const float* __restrict__ feat_down,
                   u16* __restrict__ interp_out)
{
    __shared__ u16   rbuf[TN * RS];
    __shared__ u16   ftbuf[DD * FS];
    __shared__ float xyzb[BM * 3];
    __shared__ float denp[TN * 2];
    __shared__ float invden[TN];

    const int tid = threadIdx.x;
    const int b  = blockIdx.x >> 7;
    const int n0 = (blockIdx.x & 127) * TN;

    const int nl_r = tid >> 1;
    const int half = tid & 1;
    const float* xu = xyz_up + (size_t)(b * NN + n0 + nl_r) * 3;
    const float ax = xu[0], ay = xu[1], az = xu[2];

    denp[tid] = 0.f;

    const int wave = tid >> 6;
    const int lane = tid & 63;
    const int q    = lane >> 4;
    const int nl   = lane & 15;

    f32x4 acc[2][4];
#pragma unroll
    for (int i = 0; i < 2; i++)
#pragma unroll
        for (int j = 0; j < 4; j++) acc[i][j] = (f32x4){0.f, 0.f, 0.f, 0.f};

    const int sm = (tid & 31) * 2;
    const int sd = (tid >> 5) * 8;

    for (int mc = 0; mc < MM; mc += BM) {
        __syncthreads();
        if (tid < 192) xyzb[tid] = xyz_down[(size_t)(b * MM + mc) * 3 + tid];
        {
            const float4* f0 = (const float4*)(feat_down + (size_t)(b * MM + mc + sm) * DD + sd);
            const float4* f1 = (const float4*)(feat_down + (size_t)(b * MM + mc + sm + 1) * DD + sd);
            float4 a0 = f0[0], a1 = f0[1];
            float4 b0 = f1[0], b1 = f1[1];
            float r0[8] = {a0.x, a0.y, a0.z, a0.w, a1.x, a1.y, a1.z, a1.w};
            float r1[8] = {b0.x, b0.y, b0.z, b0.w, b1.x, b1.y, b1.z, b1.w};
#pragma unroll
            for (int j = 0; j < 8; j++) {
                u32 pk = (u32)f2bf(r0[j]) | ((u32)f2bf(r1[j]) << 16);
                *(u32*)&ftbuf[(sd + j) * FS + sm] = pk;
            }
        }
        __syncthreads();
        {
            float dlc = 0.f;
#pragma unroll
            for (int s = 0; s < 4; s++) {
                bf16x8 v;
#pragma unroll
                for (int j = 0; j < 8; j++) {
                    int m = half * 32 + s * 8 + j;
                    float dx = ax - xyzb[3 * m + 0];
                    float dy = ay - xyzb[3 * m + 1];
                    float dz = az - xyzb[3 * m + 2];
                    float d = fmaf(dx, dx, fmaf(dy, dy, dz * dz)) + 1e-8f;
                    float r = __builtin_amdgcn_rcpf(d);
                    dlc += r;
                    v[j] = (short)f2bf(r);
                }
                *(bf16x8*)&rbuf[nl_r * RS + half * 32 + s * 8] = v;
            }
            denp[nl_r * 2 + half] += dlc;
        }
        __syncthreads();
        {
            const int rowbase = wave * 32;
#pragma unroll
            for (int k0 = 0; k0 < BM; k0 += 32) {
                bf16x8 a0 = *(bf16x8*)&rbuf[(rowbase + nl) * RS + k0 + q * 8];
                bf16x8 a1 = *(bf16x8*)&rbuf[(rowbase + 16 + nl) * RS + k0 + q * 8];
#pragma unroll
                for (int dt = 0; dt < 4; dt++) {
                    bf16x8 bb = *(bf16x8*)&ftbuf[(dt * 16 + nl) * FS + k0 + q * 8];
                    acc[0][dt] = __builtin_amdgcn_mfma_f32_16x16x32_bf16(a0, bb, acc[0][dt], 0, 0, 0);
                    acc[1][dt] = __builtin_amdgcn_mfma_f32_16x16x32_bf16(a1, bb, acc[1][dt], 0, 0, 0);
                }
            }
        }
    }

    __syncthreads();
    if (tid < TN) invden[tid] = 1.0f / (denp[tid * 2] + denp[tid * 2 + 1]);
    __syncthreads();
    {
        const int rowbase = wave * 32;
#pragma unroll
        for (int nt = 0; nt < 2; nt++) {
#pragma unroll
            for (int reg = 0; reg < 4; reg++) {
                int nloc = rowbase + nt * 16 + q * 4 + reg;
                float inv = invden[nloc];
                size_t gbase = (size_t)(b * NN + n0 + nloc) * DD;
#pragma unroll
                for (int dt = 0; dt < 4; dt++)
                    interp_out[gbase + dt * 16 + nl] = f2bf(acc[nt][dt][reg] * inv);
            }
        }
    }
}

#define T2 64

__global__ __launch_bounds__(256, 1)
void mlp_kernel(const float* __restrict__ feat_up,
                const u16*   __restrict__ interp,
                const float* __restrict__ W1, const float* __restrict__ b1,
                const float* __restrict__ g1, const float* __restrict__ be1,
                const float* __restrict__ m1, const float* __restrict__ v1,
                const float* __restrict__ W2, const float* __restrict__ b2,
                const float* __restrict__ g2, const float* __restrict__ be2,
                const float* __restrict__ m2, const float* __restrict__ v2,
                float* __restrict__ out)
{
    __shared__ u16 xb[T2 * 136];
    __shared__ u16 hb[T2 * 136];
    __shared__ u16 w1b[128 * 136];
    __shared__ u16 w2b[64 * 136];
    __shared__ float A1[128], Bc1[128], A2[64], Bc2[64];

    const int tid = threadIdx.x;
    const int b  = blockIdx.x >> 8;
    const int n0 = (blockIdx.x & 255) * T2;
    const int wave = tid >> 6;
    const int lane = tid & 63;
    const int q    = lane >> 4;
    const int nl   = lane & 15;

    if (tid < 128) {
        float a = g1[tid] * rsqrtf(v1[tid] + 1e-5f);
        A1[tid]  = a;
        Bc1[tid] = (b1[tid] - m1[tid]) * a + be1[tid];
    } else if (tid < 192) {
        int o = tid - 128;
        float a = g2[o] * rsqrtf(v2[o] + 1e-5f);
        A2[o]  = a;
        Bc2[o] = (b2[o] - m2[o]) * a + be2[o];
    }
    {
        const float4* src = (const float4*)(W1 + (size_t)(tid >> 1) * 128 + (tid & 1) * 64);
        u16* dst = &w1b[(tid >> 1) * 136 + (tid & 1) * 64];
#pragma unroll
        for (int i = 0; i < 8; i++)
            *(bf16x8*)(dst + 8 * i) = pack8(src[2 * i], src[2 * i + 1]);
    }
    {
        const float4* src = (const float4*)(W2 + (size_t)(tid >> 2) * 128 + (tid & 3) * 32);
        u16* dst = &w2b[(tid >> 2) * 136 + (tid & 3) * 32];
#pragma unroll
        for (int i = 0; i < 4; i++)
            *(bf16x8*)(dst + 8 * i) = pack8(src[2 * i], src[2 * i + 1]);
    }
    if (tid < 128) {
        int n = tid >> 1, hf = tid & 1;
        const float4* src = (const float4*)(feat_up + (size_t)(b * NN + n0 + n) * 64 + hf * 32);
        u16* dst = &xb[n * 136 + hf * 32];
#pragma unroll
        for (int i = 0; i < 4; i++)
            *(bf16x8*)(dst + 8 * i) = pack8(src[2 * i], src[2 * i + 1]);
    } else {
        int t2 = tid - 128;
        int n = t2 >> 1, hf = t2 & 1;
        const uint4* src = (const uint4*)(interp + (size_t)(b * NN + n0 + n) * 64 + hf * 32);
        u16* dst = &xb[n * 136 + 64 + hf * 32];
#pragma unroll
        for (int i = 0; i < 4; i++)
            *(uint4*)(dst + 8 * i) = src[i];
    }
    __syncthreads();

    f32x4 acc1[8];
#pragma unroll
    for (int i = 0; i < 8; i++) acc1[i] = (f32x4){0.f, 0.f, 0.f, 0.f};
#pragma unroll
    for (int k0 = 0; k0 < 128; k0 += 32) {
        bf16x8 a = *(bf16x8*)&xb[(wave * 16 + nl) * 136 + k0 + q * 8];
#pragma unroll
        for (int ot = 0; ot < 8; ot++) {
            bf16x8 bb = *(bf16x8*)&w1b[(ot * 16 + nl) * 136 + k0 + q * 8];
            acc1[ot] = __builtin_amdgcn_mfma_f32_16x16x32_bf16(a, bb, acc1[ot], 0, 0, 0);
        }
    }
#pragma unroll
    for (int ot = 0; ot < 8; ot++) {
        int o = ot * 16 + nl;
        float aa = A1[o], bc = Bc1[o];
#pragma unroll
        for (int reg = 0; reg < 4; reg++) {
            float v = fmaxf(fmaf(acc1[ot][reg], aa, bc), 0.f);
            hb[(wave * 16 + q * 4 + reg) * 136 + o] = f2bf(v);
        }
    }
    __syncthreads();

    f32x4 acc2[4];
#pragma unroll
    for (int i = 0; i < 4; i++) acc2[i] = (f32x4){0.f, 0.f, 0.f, 0.f};
#pragma unroll
    for (int k0 = 0; k0 < 128; k0 += 32) {
        bf16x8 a = *(bf16x8*)&hb[(wave * 16 + nl) * 136 + k0 + q * 8];
#pragma unroll
        for (int ot = 0; ot < 4; ot++) {
            bf16x8 bb = *(bf16x8*)&w2b[(ot * 16 + nl) * 136 + k0 + q * 8];
            acc2[ot] = __builtin_amdgcn_mfma_f32_16x16x32_bf16(a, bb, acc2[ot], 0, 0, 0);
        }
    }
#pragma unroll
    for (int ot = 0; ot < 4; ot++) {
        int o = ot * 16 + nl;
        float aa = A2[o], bc = Bc2[o];
#pragma unroll
        for (int reg = 0; reg < 4; reg++)
            out[(size_t)(b * NN + n0 + wave * 16 + q * 4 + reg) * 64 + o] =
                fmaf(acc2[ot][reg], aa, bc);
    }
}

extern "C" void kernel_launch(void* const* d_in, const int* in_sizes, int n_in,
                              void* d_out, int out_size, void* d_ws, size_t ws_size,
                              hipStream_t stream) {
    const float* xyz_down  = (const float*)d_in[0];
    const float* xyz_up    = (const float*)d_in[1];
    const float* feat_down = (const float*)d_in[2];
    const float* feat_up   = (const float*)d_in[3];
    const float* W1  = (const float*)d_in[4];
    const float* b1  = (const float*)d_in[5];
    const float* g1  = (const float*)d_in[6];
    const float* be1 = (const float*)d_in[7];
    const float* m1  = (const float*)d_in[8];
    const float* v1  = (const float*)d_in[9];
    const float* W2  = (const float*)d_in[10];
    const float* b2  = (const float*)d_in[11];
    const float* g2  = (const float*)d_in[12];
    const float* be2 = (const float*)d_in[13];
    const float* m2  = (const float*)d_in[14];
    const float* v2  = (const float*)d_in[15];
    float* out = (float*)d_out;
    char* ws = (char*)d_ws;

    if (ws_size >= WS_NEED) {
        u16*    fdT   = (u16*)(ws + OFF_FDT);
        float4* xyzP  = (float4*)(ws + OFF_XYZP);
        u16*    w1s   = (u16*)(ws + OFF_W1S);
        u16*    w2s   = (u16*)(ws + OFF_W2S);
        float*  bnbuf = (float*)(ws + OFF_BN);

        prep6_kernel<<<dim3(285), dim3(256), 0, stream>>>(
            xyz_down, feat_down, W1, b1, g1, be1, m1, v1,
            W2, b2, g2, be2, m2, v2, fdT, xyzP, w1s, w2s, bnbuf);
        fused11_kernel<<<dim3(BB * (NN / 256)), dim3(256), 0, stream>>>(
            xyz_up, fdT, xyzP, feat_up, w1s, w2s, bnbuf, out);
    } else {
        u16* interp = (u16*)d_ws;
        interp_kernel<<<dim3(BB * (NN / TN)), dim3(256), 0, stream>>>(
            xyz_down, xyz_up, feat_down, interp);
        mlp_kernel<<<dim3(BB * (NN / T2)), dim3(256), 0, stream>>>(
            feat_up, interp, W1, b1, g1, be1, m1, v1,
            W2, b2, g2, be2, m2, v2, out);
    }
}

// Round 6
// 140.127 us; speedup vs baseline: 1.1559x; 1.1559x over previous
//
#include <hip/hip_runtime.h>

typedef unsigned short u16;
typedef unsigned int   u32;
typedef unsigned long long u64;

typedef __attribute__((ext_vector_type(8))) short bf16x8;
typedef __attribute__((ext_vector_type(4))) float f32x4;
typedef __attribute__((ext_vector_type(2))) float f32x2;

#define BB 4
#define MM 2048
#define NN 16384
#define DD 64

__device__ __forceinline__ u16 f2bf(float f) {
    union { float f; u32 u; } v; v.f = f;
    u32 r = v.u + 0x7fffu + ((v.u >> 16) & 1u);   // RNE
    return (u16)(r >> 16);
}

// pack two floats to bf16 pair by truncation: lo16=trunc(lo), hi16=trunc(hi)
__device__ __forceinline__ u32 pack_trunc(float hi, float lo) {
    union { float f; u32 u; } a, b; a.f = hi; b.f = lo;
    return __builtin_amdgcn_perm(a.u, b.u, 0x07060302);
}

// RNE pack of two floats into a bf16 pair
__device__ __forceinline__ u32 pack_rne(float hi, float lo) {
    return (u32)f2bf(lo) | ((u32)f2bf(hi) << 16);
}

__device__ __forceinline__ bf16x8 pack8(float4 p, float4 q) {
    bf16x8 v;
    v[0] = (short)f2bf(p.x); v[1] = (short)f2bf(p.y);
    v[2] = (short)f2bf(p.z); v[3] = (short)f2bf(p.w);
    v[4] = (short)f2bf(q.x); v[5] = (short)f2bf(q.y);
    v[6] = (short)f2bf(q.z); v[7] = (short)f2bf(q.w);
    return v;
}

// ===========================================================================
// ws layout:
//   [0, 1M)      fdT  bf16 FRAG-MAJOR [b][c][h][dt][lane][8]
//                (b: batch, c: 64-m chunk 0..31, h: 32-m half, dt: d-tile,
//                 lane: (q<<4)|nl with d = dt*16+nl, m = c*64+h*32+q*8+j)
//   [1M, +128K)  xyzP pair-SoA: per pair {-2x0,-2x1,-2y0,-2y1}{-2z0,-2z1,w0,w1}
//   [.., +32K)   w1s  bf16 frag-major [kg*8+ot][lane][8]
//   [.., +16K)   w2s  bf16 frag-major [kg*4+ot][lane][8]
//   [.., +1.5K)  bn consts float[384] = A1[128] Bc1[128] A2[64] Bc2[64]
// ===========================================================================
#define OFF_FDT   0ull
#define OFF_XYZP  1048576ull
#define OFF_W1S   1179648ull
#define OFF_W2S   1212416ull
#define OFF_BN    1228800ull
#define WS_NEED   1230336ull

// ---------------------------------------------------------------------------
// prep7: 285 blocks x 256. Same as prep6 except blocks 0..255 emit fdT in
// fragment-major order so fused12's bb loads are lane-coalesced.
// ---------------------------------------------------------------------------
__global__ __launch_bounds__(256)
void prep7_kernel(const float* __restrict__ xyz_down,
                  const float* __restrict__ feat_down,
                  const float* __restrict__ W1, const float* __restrict__ b1,
                  const float* __restrict__ g1, const float* __restrict__ be1,
                  const float* __restrict__ m1, const float* __restrict__ v1,
                  const float* __restrict__ W2, const float* __restrict__ b2,
                  const float* __restrict__ g2, const float* __restrict__ be2,
                  const float* __restrict__ m2, const float* __restrict__ v2,
                  u16* __restrict__ fdT, float4* __restrict__ xyzP,
                  u16* __restrict__ w1s, u16* __restrict__ w2s,
                  float* __restrict__ bnbuf)
{
    const int blk = blockIdx.x, t = threadIdx.x;
    if (blk < 256) {
        __shared__ u16 T[32 * 72];                 // [m_local][d], stride 72
        const int b = blk >> 6, mt = blk & 63;     // 32-m tile
        const int c = mt >> 1, h = mt & 1;
        // phase A: coalesced read, convert, 16B-aligned LDS writes
        {
            const int row = t >> 3, seg = (t & 7) * 8;
            const float4* src = (const float4*)(feat_down + ((size_t)(b * MM + mt * 32 + row)) * 64 + seg);
            float4 v0 = src[0], v1 = src[1];
            bf16x8 pk = pack8(v0, v1);
            *(bf16x8*)&T[row * 72 + seg] = pk;
        }
        __syncthreads();
        // phase B: frag-major emit. t -> (dt, lane); out[j] = T[q*8+j][dt*16+nl]
        {
            const int dt = t >> 6, lane = t & 63;
            const int q = lane >> 4, nl = lane & 15;
            union { u16 hh[8]; uint4 qq; } o;
#pragma unroll
            for (int j = 0; j < 8; j++) o.hh[j] = T[(q * 8 + j) * 72 + dt * 16 + nl];
            *(uint4*)&fdT[(size_t)(b * 64 + c * 2 + h) * 2048 + dt * 512 + lane * 8] = o.qq;
        }
    } else if (blk < 272) {
        int g = (blk - 256) * 256 + t;             // pair index over 4096
        int b = g >> 10, p = g & 1023;
        const float* s = xyz_down + ((size_t)b * MM + 2 * p) * 3;
        float x0 = s[0], y0 = s[1], z0 = s[2];
        float x1 = s[3], y1 = s[4], z1 = s[5];
        float w0 = x0 * x0 + y0 * y0 + z0 * z0 + 1e-8f;
        float w1v = x1 * x1 + y1 * y1 + z1 * z1 + 1e-8f;
        xyzP[(size_t)g * 2 + 0] = make_float4(-2.f * x0, -2.f * x1, -2.f * y0, -2.f * y1);
        xyzP[(size_t)g * 2 + 1] = make_float4(-2.f * z0, -2.f * z1, w0, w1v);
    } else if (blk < 280) {
        int slot = (blk - 272) * 256 + t;          // 0..2047
        int f = slot >> 6, l = slot & 63;
        int kg = f >> 3, ot = f & 7;
        int o = ot * 16 + (l & 15), c = kg * 32 + (l >> 4) * 8;
        const float4* src = (const float4*)(W1 + (size_t)o * 128 + c);
        bf16x8 v = pack8(src[0], src[1]);
        *(bf16x8*)&w1s[(size_t)slot * 8] = v;
    } else if (blk < 284) {
        int slot = (blk - 280) * 256 + t;          // 0..1023
        int f = slot >> 6, l = slot & 63;
        int kg = f >> 2, ot = f & 3;
        int o = ot * 16 + (l & 15), c = kg * 32 + (l >> 4) * 8;
        const float4* src = (const float4*)(W2 + (size_t)o * 128 + c);
        bf16x8 v = pack8(src[0], src[1]);
        *(bf16x8*)&w2s[(size_t)slot * 8] = v;
    } else {
        if (t < 128) {
            float a = g1[t] * rsqrtf(v1[t] + 1e-5f);
            bnbuf[t] = a;
            bnbuf[128 + t] = (b1[t] - m1[t]) * a + be1[t];
        } else if (t < 192) {
            int o = t - 128;
            float a = g2[o] * rsqrtf(v2[o] + 1e-5f);
            bnbuf[256 + o] = a;
            bnbuf[320 + o] = (b2[o] - m2[o]) * a + be2[o];
        }
    }
}

// ---------------------------------------------------------------------------
// fused12: barrier-free loop, coalesced register bb. Rounds 2-5 showed every
// per-chunk-staged+barrier variant pins at ~61us with VALUBusy<=43% and no
// pipe saturated: the barrier phase-locks all waves into identical resource
// bursts. fused9 proved barrier-free runs but died on SCATTER bb loads.
// fused12 = barrier-free + COALESCED bb: prep emits fdT frag-major so each
// wave's bb fragment is one global_load_dwordx4 (1KB, L1/L2-hit), register-
// prefetched 1 chunk deep. xyz staged to LDS once (32KB, broadcast reads).
// ZERO barriers / ds_writes in the 32-chunk loop -> waves fully decoupled.
// Work split + epilogue = fused10 (proven): 8 waves, rg=wave&3 rows,
// h=wave>>2 m-half, LDS cross-half reduction, fused MLP.
// ---------------------------------------------------------------------------
__global__ __launch_bounds__(512, 4)
void fused12_kernel(const float* __restrict__ xyz_up,
                    const u16* __restrict__ fdT,
                    const float4* __restrict__ xyzP,
                    const float* __restrict__ feat_up,
                    const u16* __restrict__ w1s,
                    const u16* __restrict__ w2s,
                    const float* __restrict__ bnbuf,
                    float* __restrict__ out)
{
    // aliased LDS: interp {xzA[1024]|xzB[1024] float4 (32768B)} overlays
    // MLP {xh[128][136] u16 == of[128][68] f32 (34816B)}
    __shared__ __align__(16) char smem[34816];
    __shared__ float bnl[384];
    float4* const xzA = (float4*)smem;             // ld0 per pair
    float4* const xzB = (float4*)smem + 1024;      // ld1 per pair
    u16*   const xh   = (u16*)smem;                // [128][136]
    float* const of   = (float*)smem;              // [128][68]

    const int tid  = threadIdx.x;
    const int b    = blockIdx.x >> 7;
    const int n0   = (blockIdx.x & 127) * 128;
    const int wave = tid >> 6;
    const int lane = tid & 63;
    const int q    = lane >> 4;
    const int nl   = lane & 15;
    const int rg   = wave & 3;     // row group: rows rg*32 .. rg*32+31
    const int h    = wave >> 2;    // m-half of each chunk

    if (tid < 384) bnl[tid] = bnbuf[tid];

    // stage ALL xyz pairs for this b into LDS once: 2048 float4, 4/thread
    {
        const float4* src = xyzP + (size_t)b * 2048;
#pragma unroll
        for (int k = 0; k < 4; k++) {
            int idx = tid + k * 512;            // 0..2047
            float4 v = src[idx];
            int pair = idx >> 1;
            if (idx & 1) xzB[pair] = v; else xzA[pair] = v;
        }
    }

    // per-row xyz_up (2 row-tiles of 16 per row group)
    float ax[2], ay[2], az[2];
    f32x2 a22[2];
#pragma unroll
    for (int rt = 0; rt < 2; rt++) {
        const int row = n0 + rg * 32 + rt * 16 + nl;
        const float* xu = xyz_up + ((size_t)(b * NN + row)) * 3;
        ax[rt] = xu[0]; ay[rt] = xu[1]; az[rt] = xu[2];
        float a2 = ax[rt] * ax[rt] + ay[rt] * ay[rt] + az[rt] * az[rt];
        a22[rt] = (f32x2){a2, a2};
    }
    const f32x2 eps2 = (f32x2){1e-8f, 1e-8f};

    f32x4 acc[2][4];
#pragma unroll
    for (int rt = 0; rt < 2; rt++)
#pragma unroll
        for (int i = 0; i < 4; i++) acc[rt][i] = (f32x4){0.f, 0.f, 0.f, 0.f};
    f32x4 accd[2];
    accd[0] = (f32x4){0.f, 0.f, 0.f, 0.f};
    accd[1] = (f32x4){0.f, 0.f, 0.f, 0.f};

    bf16x8 ones;
#pragma unroll
    for (int i = 0; i < 8; i++) ones[i] = (short)0x3F80;   // bf16 1.0

    // frag-major bb base for this wave: [b][c][h][dt][lane][8]
    const u16* fdbW = fdT + (size_t)(b * 64 + h) * 2048 + (size_t)lane * 8;

    bf16x8 bbc[4], bbn[4];
#pragma unroll
    for (int dt = 0; dt < 4; dt++)
        bbc[dt] = *(const bf16x8*)(fdbW + dt * 512);

    __syncthreads();   // xz staged; the ONLY barrier before the epilogue

    for (int c = 0; c < 32; ++c) {
        // prefetch next chunk's bb frags (coalesced 1KB loads, L1/L2-hit)
        if (c + 1 < 32) {
#pragma unroll
            for (int dt = 0; dt < 4; dt++)
                bbn[dt] = *(const bf16x8*)(fdbW + (size_t)(c + 1) * 4096 + dt * 512);
        }

        u32 fr[2][4];
#pragma unroll
        for (int jp = 0; jp < 4; jp++) {
            const int pi = c * 32 + h * 16 + q * 4 + jp;
            float4 ld0 = xzA[pi];              // {-2x0,-2x1,-2y0,-2y1}
            float4 ld1 = xzB[pi];              // {-2z0,-2z1, w0, w1}
            f32x2 px = (f32x2){ld0.x, ld0.y};
            f32x2 py = (f32x2){ld0.z, ld0.w};
            f32x2 pz = (f32x2){ld1.x, ld1.y};
            f32x2 pw = (f32x2){ld1.z, ld1.w};
#pragma unroll
            for (int rt = 0; rt < 2; rt++) {
                f32x2 d = __builtin_elementwise_fma(px, (f32x2){ax[rt], ax[rt]},
                          __builtin_elementwise_fma(py, (f32x2){ay[rt], ay[rt]},
                          __builtin_elementwise_fma(pz, (f32x2){az[rt], az[rt]},
                                                    pw + a22[rt])));
                d = __builtin_elementwise_max(d, eps2);
                float r0 = __builtin_amdgcn_rcpf(d.x);
                float r1 = __builtin_amdgcn_rcpf(d.y);
                fr[rt][jp] = pack_trunc(r1, r0);
            }
        }
#pragma unroll
        for (int rt = 0; rt < 2; rt++) {
            union { u32 u[4]; bf16x8 v; } af;
            af.u[0] = fr[rt][0]; af.u[1] = fr[rt][1];
            af.u[2] = fr[rt][2]; af.u[3] = fr[rt][3];
#pragma unroll
            for (int dt = 0; dt < 4; dt++)
                acc[rt][dt] = __builtin_amdgcn_mfma_f32_16x16x32_bf16(af.v, bbc[dt], acc[rt][dt], 0, 0, 0);
            accd[rt] = __builtin_amdgcn_mfma_f32_16x16x32_bf16(af.v, ones, accd[rt], 0, 0, 0);
        }
#pragma unroll
        for (int dt = 0; dt < 4; dt++) bbc[dt] = bbn[dt];
    }

    // issue feat_up global loads early: latency hides under the reduction
    const int fur = tid >> 2, fsg = (tid & 3) * 16;
    const float4* fup = (const float4*)(feat_up + ((size_t)(b * NN + n0 + fur)) * 64 + fsg);
    float4 f0 = fup[0], f1 = fup[1], f2 = fup[2], f3 = fup[3];

    __syncthreads();   // protect smem alias: all xz reads done before of[] writes

    // cross-half reduction: upper half writes raw partials (f32) into of[]
    if (h) {
#pragma unroll
        for (int rt = 0; rt < 2; rt++)
#pragma unroll
        for (int reg = 0; reg < 4; reg++) {
            int row = rg * 32 + rt * 16 + q * 4 + reg;
#pragma unroll
            for (int dt = 0; dt < 4; dt++)
                of[row * 68 + dt * 16 + nl] = acc[rt][dt][reg];
            if (nl == 0) of[row * 68 + 64] = accd[rt][reg];
        }
    }
    __syncthreads();
    if (!h) {
#pragma unroll
        for (int rt = 0; rt < 2; rt++)
#pragma unroll
        for (int reg = 0; reg < 4; reg++) {
            int row = rg * 32 + rt * 16 + q * 4 + reg;
#pragma unroll
            for (int dt = 0; dt < 4; dt++)
                acc[rt][dt][reg] += of[row * 68 + dt * 16 + nl];
            accd[rt][reg] += of[row * 68 + 64];   // broadcast read
        }
    }
    __syncthreads();
    // lower half: normalize, write interp bf16 into xh cols 64..127
    if (!h) {
#pragma unroll
        for (int rt = 0; rt < 2; rt++)
#pragma unroll
        for (int reg = 0; reg < 4; reg++) {
            float inv = 1.0f / accd[rt][reg];
            int row = rg * 32 + rt * 16 + q * 4 + reg;
#pragma unroll
            for (int dt = 0; dt < 4; dt++)
                xh[row * 136 + 64 + dt * 16 + nl] = f2bf(acc[rt][dt][reg] * inv);
        }
    }
    // all threads: feat_up bf16 into xh cols 0..63 (16 floats each)
    {
        uint4 o0, o1;
        o0.x = pack_rne(f0.y, f0.x); o0.y = pack_rne(f0.w, f0.z);
        o0.z = pack_rne(f1.y, f1.x); o0.w = pack_rne(f1.w, f1.z);
        o1.x = pack_rne(f2.y, f2.x); o1.y = pack_rne(f2.w, f2.z);
        o1.z = pack_rne(f3.y, f3.x); o1.w = pack_rne(f3.w, f3.z);
        uint4* xd = (uint4*)&xh[fur * 136 + fsg];
        xd[0] = o0; xd[1] = o1;
    }
    __syncthreads();

    // ---------------- GEMM1: x(128x128) @ W1^T -> h (8 waves x 16 rows) ---
    f32x4 acc1[8];
#pragma unroll
    for (int i = 0; i < 8; i++) acc1[i] = (f32x4){0.f, 0.f, 0.f, 0.f};
#pragma unroll
    for (int kg = 0; kg < 4; kg++) {
        bf16x8 afr = *(bf16x8*)&xh[(wave * 16 + nl) * 136 + kg * 32 + q * 8];
#pragma unroll
        for (int ot = 0; ot < 8; ot++) {
            bf16x8 bf = *(const bf16x8*)(w1s + ((size_t)(kg * 8 + ot) * 64 + lane) * 8);
            acc1[ot] = __builtin_amdgcn_mfma_f32_16x16x32_bf16(afr, bf, acc1[ot], 0, 0, 0);
        }
    }
    // BN1 + ReLU -> bf16 h back into xh (wave-private rows -> no barrier)
#pragma unroll
    for (int ot = 0; ot < 8; ot++) {
        int o = ot * 16 + nl;
        float aa = bnl[o], bc = bnl[128 + o];
#pragma unroll
        for (int reg = 0; reg < 4; reg++) {
            float v = fmaxf(fmaf(acc1[ot][reg], aa, bc), 0.f);
            xh[(wave * 16 + q * 4 + reg) * 136 + o] = f2bf(v);
        }
    }

    // ---------------- GEMM2: h(128x128) @ W2^T -> out ----------------
    f32x4 acc2[4];
#pragma unroll
    for (int i = 0; i < 4; i++) acc2[i] = (f32x4){0.f, 0.f, 0.f, 0.f};
#pragma unroll
    for (int kg = 0; kg < 4; kg++) {
        bf16x8 afr = *(bf16x8*)&xh[(wave * 16 + nl) * 136 + kg * 32 + q * 8];
#pragma unroll
        for (int ot = 0; ot < 4; ot++) {
            bf16x8 bf = *(const bf16x8*)(w2s + ((size_t)(kg * 4 + ot) * 64 + lane) * 8);
            acc2[ot] = __builtin_amdgcn_mfma_f32_16x16x32_bf16(afr, bf, acc2[ot], 0, 0, 0);
        }
    }
    // BN2 -> f32 tile (of view, wave-private rows)
#pragma unroll
    for (int ot = 0; ot < 4; ot++) {
        int o = ot * 16 + nl;
        float aa = bnl[256 + o], bc = bnl[320 + o];
#pragma unroll
        for (int reg = 0; reg < 4; reg++)
            of[(wave * 16 + q * 4 + reg) * 68 + o] = fmaf(acc2[ot][reg], aa, bc);
    }

    // coalesced out store (rows fur in [wave*16, wave*16+16) -> wave-private)
    {
        const float4* sf = (const float4*)&of[fur * 68 + fsg];
        float4* dst = (float4*)(out + ((size_t)(b * NN + n0 + fur)) * 64 + fsg);
#pragma unroll
        for (int i = 0; i < 4; i++) dst[i] = sf[i];
    }
}

// ===========================================================================
// Fallback (round-1 kernels, proven): used when ws_size < WS_NEED.
// ===========================================================================
#define TN 128
#define BM 64
#define RS 72
#define FS 72

__global__ __launch_bounds__(256, 3)
void interp_kernel(const float* __restrict__ xyz_down,
                   const float* __restrict__ xyz_up,
                   const float* __restrict__ feat_down,
                   u16* __restrict__ interp_out)
{
    __shared__ u16   rbuf[TN * RS];
    __shared__ u16   ftbuf[DD * FS];
    __shared__ float xyzb[BM * 3];
    __shared__ float denp[TN * 2];
    __shared__ float invden[TN];

    const int tid = threadIdx.x;
    const int b  = blockIdx.x >> 7;
    const int n0 = (blockIdx.x & 127) * TN;

    const int nl_r = tid >> 1;
    const int half = tid & 1;
    const float* xu = xyz_up + (size_t)(b * NN + n0 + nl_r) * 3;
    const float ax = xu[0], ay = xu[1], az = xu[2];

    denp[tid] = 0.f;

    const int wave = tid >> 6;
    const int lane = tid & 63;
    const int q    = lane >> 4;
    const int nl   = lane & 15;

    f32x4 acc[2][4];
#pragma unroll
    for (int i = 0; i < 2; i++)
#pragma unroll
        for (int j = 0; j < 4; j++) acc[i][j] = (f32x4){0.f, 0.f, 0.f, 0.f};

    const int sm = (tid & 31) * 2;
    const int sd = (tid >> 5) * 8;

    for (int mc = 0; mc < MM; mc += BM) {
        __syncthreads();
        if (tid < 192) xyzb[tid] = xyz_down[(size_t)(b * MM + mc) * 3 + tid];
        {
            const float4* f0 = (const float4*)(feat_down + (size_t)(b * MM + mc + sm) * DD + sd);
            const float4* f1 = (const float4*)(feat_down + (size_t)(b * MM + mc + sm + 1) * DD + sd);
            float4 a0 = f0[0], a1 = f0[1];
            float4 b0 = f1[0], b1 = f1[1];
            float r0[8] = {a0.x, a0.y, a0.z, a0.w, a1.x, a1.y, a1.z, a1.w};
            float r1[8] = {b0.x, b0.y, b0.z, b0.w, b1.x, b1.y, b1.z, b1.w};
#pragma unroll
            for (int j = 0; j < 8; j++) {
                u32 pk = (u32)f2bf(r0[j]) | ((u32)f2bf(r1[j]) << 16);
                *(u32*)&ftbuf[(sd + j) * FS + sm] = pk;
            }
        }
        __syncthreads();
        {
            float dlc = 0.f;
#pragma unroll
            for (int s = 0; s < 4; s++) {
                bf16x8 v;
#pragma unroll
                for (int j = 0; j < 8; j++) {
                    int m = half * 32 + s * 8 + j;
                    float dx = ax - xyzb[3 * m + 0];
                    float dy = ay - xyzb[3 * m + 1];
                    float dz = az - xyzb[3 * m + 2];
                    float d = fmaf(dx, dx, fmaf(dy, dy, dz * dz)) + 1e-8f;
                    float r = __builtin_amdgcn_rcpf(d);
                    dlc += r;
                    v[j] = (short)f2bf(r);
                }
                *(bf16x8*)&rbuf[nl_r * RS + half * 32 + s * 8] = v;
            }
            denp[nl_r * 2 + half] += dlc;
        }
        __syncthreads();
        {
            const int rowbase = wave * 32;
#pragma unroll
            for (int k0 = 0; k0 < BM; k0 += 32) {
                bf16x8 a0 = *(bf16x8*)&rbuf[(rowbase + nl) * RS + k0 + q * 8];
                bf16x8 a1 = *(bf16x8*)&rbuf[(rowbase + 16 + nl) * RS + k0 + q * 8];
#pragma unroll
                for (int dt = 0; dt < 4; dt++) {
                    bf16x8 bb = *(bf16x8*)&ftbuf[(dt * 16 + nl) * FS + k0 + q * 8];
                    acc[0][dt] = __builtin_amdgcn_mfma_f32_16x16x32_bf16(a0, bb, acc[0][dt], 0, 0, 0);
                    acc[1][dt] = __builtin_amdgcn_mfma_f32_16x16x32_bf16(a1, bb, acc[1][dt], 0, 0, 0);
                }
            }
        }
    }

    __syncthreads();
    if (tid < TN) invden[tid] = 1.0f / (denp[tid * 2] + denp[tid * 2 + 1]);
    __syncthreads();
    {
        const int rowbase = wave * 32;
#pragma unroll
        for (int nt = 0; nt < 2; nt++) {
#pragma unroll
            for (int reg = 0; reg < 4; reg++) {
                int nloc = rowbase + nt * 16 + q * 4 + reg;
                float inv = invden[nloc];
                size_t gbase = (size_t)(b * NN + n0 + nloc) * DD;
#pragma unroll
                for (int dt = 0; dt < 4; dt++)
                    interp_out[gbase + dt * 16 + nl] = f2bf(acc[nt][dt][reg] * inv);
            }
        }
    }
}

#define T2 64

__global__ __launch_bounds__(256, 1)
void mlp_kernel(const float* __restrict__ feat_up,
                const u16*   __restrict__ interp,
                const float* __restrict__ W1, const float* __restrict__ b1,
                const float* __restrict__ g1, const float* __restrict__ be1,
                const float* __restrict__ m1, const float* __restrict__ v1,
                const float* __restrict__ W2, const float* __restrict__ b2,
                const float* __restrict__ g2, const float* __restrict__ be2,
                const float* __restrict__ m2, const float* __restrict__ v2,
                float* __restrict__ out)
{
    __shared__ u16 xb[T2 * 136];
    __shared__ u16 hb[T2 * 136];
    __shared__ u16 w1b[128 * 136];
    __shared__ u16 w2b[64 * 136];
    __shared__ float A1[128], Bc1[128], A2[64], Bc2[64];

    const int tid = threadIdx.x;
    const int b  = blockIdx.x >> 8;
    const int n0 = (blockIdx.x & 255) * T2;
    const int wave = tid >> 6;
    const int lane = tid & 63;
    const int q    = lane >> 4;
    const int nl   = lane & 15;

    if (tid < 128) {
        float a = g1[tid] * rsqrtf(v1[tid] + 1e-5f);
        A1[tid]  = a;
        Bc1[tid] = (b1[tid] - m1[tid]) * a + be1[tid];
    } else if (tid < 192) {
        int o = tid - 128;
        float a = g2[o] * rsqrtf(v2[o] + 1e-5f);
        A2[o]  = a;
        Bc2[o] = (b2[o] - m2[o]) * a + be2[o];
    }
    {
        const float4* src = (const float4*)(W1 + (size_t)(tid >> 1) * 128 + (tid & 1) * 64);
        u16* dst = &w1b[(tid >> 1) * 136 + (tid & 1) * 64];
#pragma unroll
        for (int i = 0; i < 8; i++)
            *(bf16x8*)(dst + 8 * i) = pack8(src[2 * i], src[2 * i + 1]);
    }
    {
        const float4* src = (const float4*)(W2 + (size_t)(tid >> 2) * 128 + (tid & 3) * 32);
        u16* dst = &w2b[(tid >> 2) * 136 + (tid & 3) * 32];
#pragma unroll
        for (int i = 0; i < 4; i++)
            *(bf16x8*)(dst + 8 * i) = pack8(src[2 * i], src[2 * i + 1]);
    }
    if (tid < 128) {
        int n = tid >> 1, hf = tid & 1;
        const float4* src = (const float4*)(feat_up + (size_t)(b * NN + n0 + n) * 64 + hf * 32);
        u16* dst = &xb[n * 136 + hf * 32];
#pragma unroll
        for (int i = 0; i < 4; i++)
            *(bf16x8*)(dst + 8 * i) = pack8(src[2 * i], src[2 * i + 1]);
    } else {
        int t2 = tid - 128;
        int n = t2 >> 1, hf = t2 & 1;
        const uint4* src = (const uint4*)(interp + (size_t)(b * NN + n0 + n) * 64 + hf * 32);
        u16* dst = &xb[n * 136 + 64 + hf * 32];
#pragma unroll
        for (int i = 0; i < 4; i++)
            *(uint4*)(dst + 8 * i) = src[i];
    }
    __syncthreads();

    f32x4 acc1[8];
#pragma unroll
    for (int i = 0; i < 8; i++) acc1[i] = (f32x4){0.f, 0.f, 0.f, 0.f};
#pragma unroll
    for (int k0 = 0; k0 < 128; k0 += 32) {
        bf16x8 a = *(bf16x8*)&xb[(wave * 16 + nl) * 136 + k0 + q * 8];
#pragma unroll
        for (int ot = 0; ot < 8; ot++) {
            bf16x8 bb = *(bf16x8*)&w1b[(ot * 16 + nl) * 136 + k0 + q * 8];
            acc1[ot] = __builtin_amdgcn_mfma_f32_16x16x32_bf16(a, bb, acc1[ot], 0, 0, 0);
        }
    }
#pragma unroll
    for (int ot = 0; ot < 8; ot++) {
        int o = ot * 16 + nl;
        float aa = A1[o], bc = Bc1[o];
#pragma unroll
        for (int reg = 0; reg < 4; reg++) {
            float v = fmaxf(fmaf(acc1[ot][reg], aa, bc), 0.f);
            hb[(wave * 16 + q * 4 + reg) * 136 + o] = f2bf(v);
        }
    }
    __syncthreads();

    f32x4 acc2[4];
#pragma unroll
    for (int i = 0; i < 4; i++) acc2[i] = (f32x4){0.f, 0.f, 0.f, 0.f};
#pragma unroll
    for (int k0 = 0; k0 < 128; k0 += 32) {
        bf16x8 a = *(bf16x8*)&hb[(wave * 16 + nl) * 136 + k0 + q * 8];
#pragma unroll
        for (int ot = 0; ot < 4; ot++) {
            bf16x8 bb = *(bf16x8*)&w2b[(ot * 16 + nl) * 136 + k0 + q * 8];
            acc2[ot] = __builtin_amdgcn_mfma_f32_16x16x32_bf16(a, bb, acc2[ot], 0, 0, 0);
        }
    }
#pragma unroll
    for (int ot = 0; ot < 4; ot++) {
        int o = ot * 16 + nl;
        float aa = A2[o], bc = Bc2[o];
#pragma unroll
        for (int reg = 0; reg < 4; reg++)
            out[(size_t)(b * NN + n0 + wave * 16 + q * 4 + reg) * 64 + o] =
                fmaf(acc2[ot][reg], aa, bc);
    }
}

extern "C" void kernel_launch(void* const* d_in, const int* in_sizes, int n_in,
                              void* d_out, int out_size, void* d_ws, size_t ws_size,
                              hipStream_t stream) {
    const float* xyz_down  = (const float*)d_in[0];
    const float* xyz_up    = (const float*)d_in[1];
    const float* feat_down = (const float*)d_in[2];
    const float* feat_up   = (const float*)d_in[3];
    const float* W1  = (const float*)d_in[4];
    const float* b1  = (const float*)d_in[5];
    const float* g1  = (const float*)d_in[6];
    const float* be1 = (const float*)d_in[7];
    const float* m1  = (const float*)d_in[8];
    const float* v1  = (const float*)d_in[9];
    const float* W2  = (const float*)d_in[10];
    const float* b2  = (const float*)d_in[11];
    const float* g2  = (const float*)d_in[12];
    const float* be2 = (const float*)d_in[13];
    const float* m2  = (const float*)d_in[14];
    const float* v2  = (const float*)d_in[15];
    float* out = (float*)d_out;
    char* ws = (char*)d_ws;

    if (ws_size >= WS_NEED) {
        u16*    fdT   = (u16*)(ws + OFF_FDT);
        float4* xyzP  = (float4*)(ws + OFF_XYZP);
        u16*    w1s   = (u16*)(ws + OFF_W1S);
        u16*    w2s   = (u16*)(ws + OFF_W2S);
        float*  bnbuf = (float*)(ws + OFF_BN);

        prep7_kernel<<<dim3(285), dim3(256), 0, stream>>>(
            xyz_down, feat_down, W1, b1, g1, be1, m1, v1,
            W2, b2, g2, be2, m2, v2, fdT, xyzP, w1s, w2s, bnbuf);
        fused12_kernel<<<dim3(BB * (NN / 128)), dim3(512), 0, stream>>>(
            xyz_up, fdT, xyzP, feat_up, w1s, w2s, bnbuf, out);
    } else {
        u16* interp = (u16*)d_ws;
        interp_kernel<<<dim3(BB * (NN / TN)), dim3(256), 0, stream>>>(
            xyz_down, xyz_up, feat_down, interp);
        mlp_kernel<<<dim3(BB * (NN / T2)), dim3(256), 0, stream>>>(
            feat_up, interp, W1, b1, g1, be1, m1, v1,
            W2, b2, g2, be2, m2, v2, out);
    }
}